// Round 1
// baseline (95.226 us; speedup 1.0000x reference)
//
#include <hip/hip_runtime.h>
#include <math.h>

#define PSZ 65
#define PSTRIDE 67   // LDS patch row stride (odd -> conflict-free row-per-lane reads)
#define PROW 33      // LDS partial row stride (odd -> conflict-free per-lane row stores)

__device__ __forceinline__ float fast_atan2f(float y, float x) {
    float ax = fabsf(x), ay = fabsf(y);
    float mx = fmaxf(ax, ay);
    float mn = fminf(ax, ay);
    float a = mn * __builtin_amdgcn_rcpf(fmaxf(mx, 1e-30f));
    float s = a * a;
    float r = fmaf(s, fmaf(s, fmaf(s, fmaf(s, fmaf(s, -0.0117212f, 0.05265332f),
                    -0.11643287f), 0.19354346f), -0.33262347f), 0.99997726f) * a;
    r = (ay > ax) ? (1.57079637f - r) : r;
    r = (x < 0.0f) ? (3.14159274f - r) : r;
    return copysignf(r, y);
}

// One block (64 threads, 1 wave) per patch. 3072 patches.
__global__ __launch_bounds__(64)
void sift_kernel(const float* __restrict__ in, float* __restrict__ out) {
    __shared__ float patch[PSZ * PSTRIDE];
    __shared__ float part[PSZ * PROW];
    __shared__ float gauss[66];

    const int m   = blockIdx.x;
    const int tid = threadIdx.x;

    // patch m -> (b*C+c, i, j): m = bc*64 + i*8 + j
    const int bc = m >> 6;
    const int ij = m & 63;
    const int pi = ij >> 3, pj = ij & 7;
    const float* src = in + (size_t)bc * (520 * 520) + pi * 65 * 520 + pj * 65;

    // ---- stage patch to LDS (coalesced within rows) ----
    for (int k = tid; k < PSZ * PSZ; k += 64) {
        int y = k / 65;
        int x = k - y * 65;
        patch[y * PSTRIDE + x] = src[y * 520 + x];
    }

    // ---- normalized 1D gaussian, sigma = 65/sqrt(2) => 2*sigma^2 = 4225 ----
    {
        float d = (float)(tid - 32);
        float e = __expf(-(d * d) * (1.0f / 4225.0f));
        float ssum = e;
        #pragma unroll
        for (int off = 32; off > 0; off >>= 1) ssum += __shfl_xor(ssum, off, 64);
        const float e64 = __expf(-1024.0f / 4225.0f);
        float inv = 1.0f / (ssum + e64);
        gauss[tid] = e * inv;
        if (tid == 0) gauss[64] = e64 * inv;
    }
    if (tid < 32) part[64 * PROW + tid] = 0.0f;
    __syncthreads();

    // ---- main pass: lane = row r (0..63), accumulate acc[sx][ang] in regs ----
    {
        const int r = tid;
        const float gr = gauss[r];
        const int rm = (r == 0) ? 0 : r - 1;
        const int rp = r + 1;  // r <= 63 so rp <= 64, in range

        float acc[4][8];
        #pragma unroll
        for (int s = 0; s < 4; ++s)
            #pragma unroll
            for (int a = 0; a < 8; ++a) acc[s][a] = 0.0f;

        #pragma unroll
        for (int sx = 0; sx < 4; ++sx) {
            const int c0 = (sx * 16 - 6 < 0) ? 0 : sx * 16 - 6;
            const int c1 = (sx * 16 + 19 > 64) ? 64 : sx * 16 + 19;
            float xl = patch[r * PSTRIDE + ((c0 > 0) ? c0 - 1 : 0)];
            float xc = patch[r * PSTRIDE + c0];
            #pragma unroll 2
            for (int c = c0; c <= c1; ++c) {
                float xr = patch[r * PSTRIDE + ((c < 64) ? c + 1 : 64)];
                float xu = patch[rm * PSTRIDE + c];
                float xd = patch[rp * PSTRIDE + c];
                float gx = 0.5f * (xr - xl);
                float gy = 0.5f * (xd - xu);
                float mag = sqrtf(fmaf(gx, gx, fmaf(gy, gy, 1e-10f)));
                float ang = fast_atan2f(gy, gx + 1e-10f);
                float o   = fmaf(ang, 1.27323954f, 8.0f);   // 4/pi * ang + 8, in (4,12]
                float bf  = floorf(o);
                float wo1 = o - bf;
                int b0 = (int)bf; b0 = (b0 >= 8) ? b0 - 8 : b0;
                int b1 = (b0 == 7) ? 0 : b0 + 1;
                float u  = (float)(c - sx * 16 + 6);
                float wc = (13.0f - fabsf(u - 12.5f)) * (1.0f / 13.0f);
                float m2 = mag * gr * gauss[c] * wc;
                float p0 = (1.0f - wo1) * m2;
                float p1 = wo1 * m2;
                #pragma unroll
                for (int a = 0; a < 8; ++a) {
                    float add = (a == b0) ? p0 : ((a == b1) ? p1 : 0.0f);
                    acc[sx][a] += add;
                }
                xl = xc; xc = xr;
            }
        }
        #pragma unroll
        for (int sx = 0; sx < 4; ++sx)
            #pragma unroll
            for (int a = 0; a < 8; ++a)
                part[r * PROW + sx * 8 + a] = acc[sx][a];
    }

    // ---- row 64, column-parallel, LDS atomics into part[64][*] ----
    for (int c = tid; c < 65; c += 64) {
        float xl = patch[64 * PSTRIDE + ((c > 0) ? c - 1 : 0)];
        float xr = patch[64 * PSTRIDE + ((c < 64) ? c + 1 : 64)];
        float xu = patch[63 * PSTRIDE + c];
        float xd = patch[64 * PSTRIDE + c];   // replicate pad below
        float gx = 0.5f * (xr - xl);
        float gy = 0.5f * (xd - xu);
        float mag = sqrtf(fmaf(gx, gx, fmaf(gy, gy, 1e-10f)));
        float ang = fast_atan2f(gy, gx + 1e-10f);
        float o   = fmaf(ang, 1.27323954f, 8.0f);
        float bf  = floorf(o);
        float wo1 = o - bf;
        int b0 = (int)bf; b0 = (b0 >= 8) ? b0 - 8 : b0;
        int b1 = (b0 == 7) ? 0 : b0 + 1;
        float magw = mag * gauss[64] * gauss[c];
        int sxhi = (c + 6) >> 4;      if (sxhi > 3) sxhi = 3;
        int sxlo = (c - 19 + 15) >> 4; if (sxlo < 0) sxlo = 0;  // ceil((c-19)/16)
        for (int sx = sxlo; sx <= sxhi; ++sx) {
            float u  = (float)(c - sx * 16 + 6);
            float wc = (13.0f - fabsf(u - 12.5f)) * (1.0f / 13.0f);
            float m2 = magw * wc;
            atomicAdd(&part[64 * PROW + sx * 8 + b0], (1.0f - wo1) * m2);
            atomicAdd(&part[64 * PROW + sx * 8 + b1], wo1 * m2);
        }
    }
    __syncthreads();

    // ---- row pooling: output o = a*16 + sy*4 + sx; lane t owns o=t and o=t+64 ----
    float v[2];
    #pragma unroll
    for (int h = 0; h < 2; ++h) {
        int o  = tid + h * 64;
        int a  = o >> 4;
        int sy = (o >> 2) & 3;
        int sx = o & 3;
        int r0 = sy * 16 - 6;  if (r0 < 0) r0 = 0;
        int r1 = sy * 16 + 19; if (r1 > 64) r1 = 64;
        float s = 0.0f;
        #pragma unroll 2
        for (int k = 0; k < 26; ++k) {
            int r = r0 + k;
            if (r <= r1) {
                float u  = (float)(r - sy * 16 + 6);
                float wr = (13.0f - fabsf(u - 12.5f)) * (1.0f / 13.0f);
                s = fmaf(wr, part[r * PROW + sx * 8 + a], s);
            }
        }
        v[h] = s;
    }

    // ---- L2 -> clip(0.2) -> L2, then store ----
    float ss = v[0] * v[0] + v[1] * v[1];
    #pragma unroll
    for (int off = 32; off > 0; off >>= 1) ss += __shfl_xor(ss, off, 64);
    float sc = 1.0f / fmaxf(sqrtf(ss), 1e-12f);
    v[0] = fminf(fmaxf(v[0] * sc, 0.0f), 0.2f);
    v[1] = fminf(fmaxf(v[1] * sc, 0.0f), 0.2f);
    ss = v[0] * v[0] + v[1] * v[1];
    #pragma unroll
    for (int off = 32; off > 0; off >>= 1) ss += __shfl_xor(ss, off, 64);
    sc = 1.0f / fmaxf(sqrtf(ss), 1e-12f);
    out[(size_t)m * 128 + tid]      = v[0] * sc;
    out[(size_t)m * 128 + tid + 64] = v[1] * sc;
}

extern "C" void kernel_launch(void* const* d_in, const int* in_sizes, int n_in,
                              void* d_out, int out_size, void* d_ws, size_t ws_size,
                              hipStream_t stream) {
    const float* in = (const float*)d_in[0];
    float* out = (float*)d_out;
    sift_kernel<<<3072, 64, 0, stream>>>(in, out);
}

// Round 2
// 81.921 us; speedup vs baseline: 1.1624x; 1.1624x over previous
//
#include <hip/hip_runtime.h>
#include <math.h>

template<int N> struct IC { static constexpr int v = N; };

__device__ __forceinline__ float fast_atan2f(float y, float x) {
    float ax = fabsf(x), ay = fabsf(y);
    float mx = fmaxf(ax, ay);
    float mn = fminf(ax, ay);
    float a = mn * __builtin_amdgcn_rcpf(fmaxf(mx, 1e-30f));
    float s = a * a;
    float r = fmaf(s, fmaf(s, fmaf(s, fmaf(s, fmaf(s, -0.0117212f, 0.05265332f),
                    -0.11643287f), 0.19354346f), -0.33262347f), 0.99997726f) * a;
    r = (ay > ax) ? (1.57079637f - r) : r;
    r = (x < 0.0f) ? (3.14159274f - r) : r;
    return copysignf(r, y);
}

// One block (64 threads, 1 wave) per patch; lane = column, iterate rows.
// No patch staging: rows stream through rolling registers (coalesced loads),
// horizontal neighbors via wave shuffles. LDS holds only the 65x32 column
// partials -> ~8.8 KB/block -> occupancy grid-limited at 12 waves/CU.
__global__ __launch_bounds__(64)
void sift_kernel(const float* __restrict__ in, float* __restrict__ out) {
    __shared__ float part[65 * 33];   // [column][sy*8+a], stride 33 (2-way banks = free)
    __shared__ float gauss[65];

    const int tid = threadIdx.x;
    const int m   = blockIdx.x;
    const int bc  = m >> 6;
    const int ij  = m & 63;
    const float* src = in + (size_t)bc * (520 * 520) + (ij >> 3) * (65 * 520) + (ij & 7) * 65;

    // ---- normalized 1D gaussian, sigma = 65/sqrt(2) => 2*sigma^2 = 4225 ----
    float dd = (float)(tid - 32);
    float e  = __expf(-(dd * dd) * (1.0f / 4225.0f));
    float ssum = e;
    #pragma unroll
    for (int off = 32; off > 0; off >>= 1) ssum += __shfl_xor(ssum, off, 64);
    const float e64c = __expf(-1024.0f / 4225.0f);
    float inv = 1.0f / (ssum + e64c);
    float gc  = e * inv;      // gauss[column = tid]
    float g64 = e64c * inv;   // gauss[64]
    gauss[tid] = gc;
    if (tid == 0) gauss[64] = g64;
    if (tid < 32) part[64 * 33 + tid] = 0.0f;
    __syncthreads();

    float acc[4][8];
    #pragma unroll
    for (int sy = 0; sy < 4; ++sy)
        #pragma unroll
        for (int a = 0; a < 8; ++a) acc[sy][a] = 0.0f;

    // rolling rows: xu = row r-1 (replicate at r=0), xcv = row r, xdv = row r+1
    float xu  = src[tid];
    float xcv = xu;
    float xdv = src[520 + tid];

    auto body = [&](int r, auto A_, auto B_) {
        constexpr int A = decltype(A_)::v;
        constexpr int B = decltype(B_)::v;
        float br64 = src[r * 520 + 64];     // column-64 value, broadcast (1 txn)
        float gr   = gauss[r];
        float xl = __shfl_up(xcv, 1);   xl = (tid == 0)  ? xcv  : xl;
        float xr = __shfl_down(xcv, 1); xr = (tid == 63) ? br64 : xr;
        float gx = 0.5f * (xr - xl);
        float gy = 0.5f * (xdv - xu);
        float mag = sqrtf(fmaf(gx, gx, fmaf(gy, gy, 1e-10f)));
        float ang = fast_atan2f(gy, gx + 1e-10f);
        float o   = fmaf(ang, 1.27323954f, 8.0f);   // in (4,12]
        float bf  = floorf(o);
        float wo1 = o - bf;
        int b0 = (int)bf; b0 = (b0 >= 8) ? b0 - 8 : b0;
        int b1 = (b0 == 7) ? 0 : b0 + 1;
        float magw = mag * gr * gc;
        float q0 = (1.0f - wo1) * magw;
        float q1 = wo1 * magw;
        float uA = (float)(r - 16 * A + 6);
        float wA = (13.0f - fabsf(uA - 12.5f)) * (1.0f / 13.0f);
        float wB = 0.0f;
        if constexpr (B >= 0) {
            float uB = (float)(r - 16 * B + 6);
            wB = (13.0f - fabsf(uB - 12.5f)) * (1.0f / 13.0f);
        }
        #pragma unroll
        for (int a = 0; a < 8; ++a) {
            float sel = (a == b0) ? q0 : ((a == b1) ? q1 : 0.0f);
            acc[A][a] = fmaf(sel, wA, acc[A][a]);
            if constexpr (B >= 0) acc[B][a] = fmaf(sel, wB, acc[B][a]);
        }
        xu = xcv; xcv = xdv;
        int rn = (r + 2 <= 64) ? r + 2 : 64;    // clamped -> always in-bounds
        xdv = src[rn * 520 + tid];
    };

    // row windows (sy): [16sy-6, 16sy+19] clamped; compile-time partition
    for (int r = 0;  r < 10; ++r) body(r, IC<0>{}, IC<-1>{});
    for (int r = 10; r < 20; ++r) body(r, IC<0>{}, IC<1>{});
    for (int r = 20; r < 26; ++r) body(r, IC<1>{}, IC<-1>{});
    for (int r = 26; r < 36; ++r) body(r, IC<1>{}, IC<2>{});
    for (int r = 36; r < 42; ++r) body(r, IC<2>{}, IC<-1>{});
    for (int r = 42; r < 52; ++r) body(r, IC<2>{}, IC<3>{});
    for (int r = 52; r < 65; ++r) body(r, IC<3>{}, IC<-1>{});

    // store column partials (lane-private column)
    #pragma unroll
    for (int sy = 0; sy < 4; ++sy)
        #pragma unroll
        for (int a = 0; a < 8; ++a)
            part[tid * 33 + sy * 8 + a] = acc[sy][a];

    // ---- column 64: lane = row, atomics into part[64][*] ----
    for (int rr = tid; rr < 65; rr += 64) {
        int rm = (rr > 0)  ? rr - 1 : 0;
        int rp = (rr < 64) ? rr + 1 : 64;
        float xc64 = src[rr * 520 + 64];
        float xl   = src[rr * 520 + 63];
        float xuu  = src[rm * 520 + 64];
        float xdd  = src[rp * 520 + 64];
        float gx = 0.5f * (xc64 - xl);          // xr = replicate = xc64
        float gy = 0.5f * (xdd - xuu);
        float mag = sqrtf(fmaf(gx, gx, fmaf(gy, gy, 1e-10f)));
        float ang = fast_atan2f(gy, gx + 1e-10f);
        float o   = fmaf(ang, 1.27323954f, 8.0f);
        float bf  = floorf(o);
        float wo1 = o - bf;
        int b0 = (int)bf; b0 = (b0 >= 8) ? b0 - 8 : b0;
        int b1 = (b0 == 7) ? 0 : b0 + 1;
        float magw = mag * gauss[rr] * g64;
        float q0 = (1.0f - wo1) * magw;
        float q1 = wo1 * magw;
        int sylo = (rr - 4) >> 4; if (sylo < 0) sylo = 0;   // ceil((rr-19)/16)
        int syhi = (rr + 6) >> 4; if (syhi > 3) syhi = 3;
        for (int sy = sylo; sy <= syhi; ++sy) {
            float u  = (float)(rr - 16 * sy + 6);
            float wr = (13.0f - fabsf(u - 12.5f)) * (1.0f / 13.0f);
            atomicAdd(&part[64 * 33 + sy * 8 + b0], q0 * wr);
            atomicAdd(&part[64 * 33 + sy * 8 + b1], q1 * wr);
        }
    }
    __syncthreads();

    // ---- column pooling: output o = a*16 + sy*4 + sx ----
    float v[2];
    #pragma unroll
    for (int h = 0; h < 2; ++h) {
        int o  = tid + h * 64;
        int a  = o >> 4;
        int sy = (o >> 2) & 3;
        int sx = o & 3;
        float s = 0.0f;
        #pragma unroll 2
        for (int k = 0; k < 26; ++k) {
            int c = sx * 16 - 6 + k;
            if ((unsigned)c <= 64u) {
                float wc = (13.0f - fabsf((float)k - 12.5f)) * (1.0f / 13.0f);
                s = fmaf(wc, part[c * 33 + sy * 8 + a], s);
            }
        }
        v[h] = s;
    }

    // ---- L2 -> clip(0.2) -> L2, store ----
    float ss = v[0] * v[0] + v[1] * v[1];
    #pragma unroll
    for (int off = 32; off > 0; off >>= 1) ss += __shfl_xor(ss, off, 64);
    float sc = 1.0f / fmaxf(sqrtf(ss), 1e-12f);
    v[0] = fminf(fmaxf(v[0] * sc, 0.0f), 0.2f);
    v[1] = fminf(fmaxf(v[1] * sc, 0.0f), 0.2f);
    ss = v[0] * v[0] + v[1] * v[1];
    #pragma unroll
    for (int off = 32; off > 0; off >>= 1) ss += __shfl_xor(ss, off, 64);
    sc = 1.0f / fmaxf(sqrtf(ss), 1e-12f);
    out[(size_t)m * 128 + tid]      = v[0] * sc;
    out[(size_t)m * 128 + tid + 64] = v[1] * sc;
}

extern "C" void kernel_launch(void* const* d_in, const int* in_sizes, int n_in,
                              void* d_out, int out_size, void* d_ws, size_t ws_size,
                              hipStream_t stream) {
    const float* in = (const float*)d_in[0];
    float* out = (float*)d_out;
    sift_kernel<<<3072, 64, 0, stream>>>(in, out);
}